// Round 1
// 1926.244 us; speedup vs baseline: 1.0196x; 1.0196x over previous
//
#include <hip/hip_runtime.h>

// LTC RNN (LiquidNeuralNetwork): B=512, S=512, H=128, 2 layers, RK4.
// Round 3: lgkm-only barriers + x-proj pipelining.
//  - All in-loop __syncthreads() replaced by {s_waitcnt lgkmcnt(0); s_barrier}.
//    __syncthreads' workgroup fence drains vmcnt(0), putting the seq HBM
//    prefetch latency on the slot-A critical path every step. lgkm-only
//    barriers keep global loads in flight across slots (counted-vmcnt idea).
//  - x-projection (u0/gx0 = [Win0;Wg0x]*x) moved off slot A's critical prefix:
//    xt double-buffered, x(i+1) staged in slot A, XPROJ(i+1) computed in slot B
//    after the gate (dead-ILP region), registers committed in slot D.
// Structure otherwise = round 2b: 32 blocks x 512 threads, waves 0-3 = L0 at
// step t, waves 4-7 = L1 at step t-1 (lag-1 pipeline), 4 slots/step, each wave
// owns 4 row-tiles so one B-frag LDS read feeds 4 MFMAs.

typedef _Float16 f16;
typedef _Float16 f16x4 __attribute__((ext_vector_type(4)));
typedef _Float16 f16x8 __attribute__((ext_vector_type(8)));
typedef float f32x4 __attribute__((ext_vector_type(4)));

#define NSTEP 512
#define OFF_A0 0
#define OFF_A1 32768
#define OFF_AIO 65536
#define OFF_AX 98304
#define W_TOTAL 122880

// LDS byte offsets. hh buffers: [16 cols][136 f16] = 4352 B each.
#define HQ0 0
#define HQ1 4352
#define L0A 8704
#define L0B 13056
#define L1A 17408
#define L1B 21760
#define L1H 26112
#define XT0 30464
#define XT1 32768
#define SMEM_BYTES 35072

__device__ __forceinline__ float rcp_f(float x) { return __builtin_amdgcn_rcpf(x); }
__device__ __forceinline__ float tanh_f(float x) {
  float e = __expf(2.f * x);
  return 1.f - 2.f * rcp_f(e + 1.f);
}
// sigmoid(t) for t in [-1,1] (t = tanh(...)): odd Taylor of 0.5+0.5*tanh(t/2), |err|<3e-6
__device__ __forceinline__ float sig_poly(float t) {
  float s = t * t;
  float p = fmaf(s, 2.1356861e-5f, -2.1081349e-4f);
  p = fmaf(s, p, 2.0833333e-3f);
  p = fmaf(s, p, -2.0833333e-2f);
  p = fmaf(s, p, 0.25f);
  return fmaf(t, p, 0.5f);
}

// lgkm-only barrier: LDS produce->consume needs lgkmcnt(0)+s_barrier only.
// Crucially does NOT drain vmcnt, so seq prefetch loads stay in flight.
#define BAR()                                            \
  do {                                                   \
    asm volatile("s_waitcnt lgkmcnt(0)" ::: "memory");   \
    __builtin_amdgcn_s_barrier();                        \
  } while (0)

// Pack all recurrent-loop weights into f16 MFMA A-fragments.
// A-frag (16x16x32): A[m=lane&15][k=(lane>>4)*8+j], row-tile T = rows 16T..16T+15.
// A0 @0      [T8][sel2][kc4][lane64][j8]  sel0=Wg0 h-part, sel1=Wrec0
// A1 @32768  same                          sel0=Wg1 h-part, sel1=Wrec1
// AIO@65536  same                          sel0=Win1,       sel1=Wg1 x-part
// AX @98304  [T8][sel2][kc3][lane64][j8]  sel0=Win0,       sel1=Wg0 x-part (K=96)
__global__ __launch_bounds__(256) void prep_kernel(
    const float* __restrict__ Win0, const float* __restrict__ Wrec0,
    const float* __restrict__ Wg0, const float* __restrict__ Win1,
    const float* __restrict__ Wrec1, const float* __restrict__ Wg1,
    f16* __restrict__ W) {
  int i = blockIdx.x * 256 + threadIdx.x;
  if (i >= W_TOTAL) return;
  if (i < OFF_AX) {
    int sec = i >> 15;
    int r = i & 32767;
    int j = r & 7, lane = (r >> 3) & 63, kc = (r >> 9) & 3, sel = (r >> 11) & 1,
        w = (r >> 12) & 7;
    int row = w * 16 + (lane & 15);
    int k = kc * 32 + ((lane >> 4) << 3) + j;
    float v;
    if (sec == 0)
      v = sel ? Wrec0[row * 128 + k] : Wg0[row * 224 + 96 + k];
    else if (sec == 1)
      v = sel ? Wrec1[row * 128 + k] : Wg1[row * 256 + 128 + k];
    else
      v = sel ? Wg1[row * 256 + k] : Win1[row * 128 + k];
    W[i] = (f16)v;
  } else {
    int r = i - OFF_AX;
    int j = r & 7, lane = (r >> 3) & 63, g = r >> 9;
    int kc = g % 3, sg = g / 3;
    int sel = sg & 1, w = sg >> 1;
    int row = w * 16 + (lane & 15);
    int k = kc * 32 + ((lane >> 4) << 3) + j;
    W[i] = (f16)(sel ? Wg0[row * 224 + k] : Win0[row * 96 + k]);
  }
}

#define MFMA16(A, B, C) __builtin_amdgcn_mfma_f32_16x16x32_f16((A), (B), (C), 0, 0, 0)
#define ZERO4 ((f32x4){0.f, 0.f, 0.f, 0.f})

// 2-tile matvec accumulate: ga/ra[i2] += {awg,awr}[i2] * B-frag(SRC). One B-frag
// read feeds 4 MFMAs (the round-2 LDS amortization).
#define MM2(SRC)                                                    \
  {                                                                 \
    const f16* bp_ = (SRC) + c * 136 + 8 * q;                       \
    _Pragma("unroll") for (int kc_ = 0; kc_ < 4; ++kc_) {           \
      f16x8 bf_ = *(const f16x8*)(bp_ + kc_ * 32);                  \
      ga[0] = MFMA16(awg[0][kc_], bf_, ga[0]);                      \
      ra[0] = MFMA16(awr[0][kc_], bf_, ra[0]);                      \
      ga[1] = MFMA16(awg[1][kc_], bf_, ga[1]);                      \
      ra[1] = MFMA16(awr[1][kc_], bf_, ra[1]);                      \
    }                                                               \
  }

// io / input projection with the au/ag2 fragment set (KCN k-chunks) into ga/ra.
#define MMIO(SRC, KCN)                                              \
  {                                                                 \
    const f16* bp_ = (SRC) + c * 136 + 8 * q;                       \
    _Pragma("unroll") for (int kc_ = 0; kc_ < (KCN); ++kc_) {       \
      f16x8 bf_ = *(const f16x8*)(bp_ + kc_ * 32);                  \
      ga[0] = MFMA16(au[0][kc_], bf_, ga[0]);                       \
      ra[0] = MFMA16(ag2[0][kc_], bf_, ra[0]);                      \
      ga[1] = MFMA16(au[1][kc_], bf_, ga[1]);                       \
      ra[1] = MFMA16(ag2[1][kc_], bf_, ra[1]);                      \
    }                                                               \
  }

// L0 x-projection (K=96: 2 chunks from x-tile + ctx) -> UD (=Win0*x),
// GD (=Wg0x*x + bg). Uses ga/ra as temporaries; off the recurrent path.
#define XPROJ(XSRC, UD, GD)                                         \
  {                                                                 \
    ZACC;                                                           \
    f16x8 bx0_ = *(const f16x8*)((XSRC) + c * 72 + 8 * q);          \
    f16x8 bx1_ = *(const f16x8*)((XSRC) + c * 72 + 32 + 8 * q);     \
    _Pragma("unroll") for (int i2_ = 0; i2_ < 2; ++i2_) {           \
      ga[i2_] = MFMA16(au[i2_][0], bx0_, ga[i2_]);                  \
      ra[i2_] = MFMA16(ag2[i2_][0], bx0_, ra[i2_]);                 \
      ga[i2_] = MFMA16(au[i2_][1], bx1_, ga[i2_]);                  \
      ra[i2_] = MFMA16(ag2[i2_][1], bx1_, ra[i2_]);                 \
      ga[i2_] = MFMA16(au[i2_][2], bctx, ga[i2_]);                  \
      ra[i2_] = MFMA16(ag2[i2_][2], bctx, ra[i2_]);                 \
      (UD)[i2_] = ga[i2_];                                          \
      _Pragma("unroll") for (int r_ = 0; r_ < 4; ++r_)              \
        (GD)[i2_][r_] = ra[i2_][r_] + bgv[i2_][r_];                 \
    }                                                               \
  }

// RK stage body: gate math on 8 (gate,rec) pairs, ksum += WC*k, eval point
// hhc = h + HC*k, write f16 eval point to DST.
#define GATEALL(WC, HC, DST)                                        \
  _Pragma("unroll") for (int i2_ = 0; i2_ < 2; ++i2_) {             \
    f16x4 hv_;                                                      \
    _Pragma("unroll") for (int r_ = 0; r_ < 4; ++r_) {              \
      float th_ = tanh_f(ga[i2_][r_] + gx[i2_][r_]);                \
      float gt_ = sig_poly(th_);                                    \
      float kk_ = fmaf(gt_, ra[i2_][r_],                            \
                       fmaf(-itv[i2_][r_], hhc[i2_][r_], u[i2_][r_])); \
      ksum[i2_][r_] = fmaf((WC), kk_, ksum[i2_][r_]);               \
      float hn_ = fmaf((HC), kk_, hst[i2_][r_]);                    \
      hhc[i2_][r_] = hn_;                                           \
      hv_[r_] = (f16)hn_;                                           \
    }                                                               \
    *(f16x4*)((DST) + c * 136 + jb[i2_]) = hv_;                     \
  }

// RK stage 4: h_new = tanh(h + ksum/6), becomes both state and next stage-1 eval.
#define GATEFIN(DST)                                                \
  _Pragma("unroll") for (int i2_ = 0; i2_ < 2; ++i2_) {             \
    f16x4 hv_;                                                      \
    _Pragma("unroll") for (int r_ = 0; r_ < 4; ++r_) {              \
      float th_ = tanh_f(ga[i2_][r_] + gx[i2_][r_]);                \
      float gt_ = sig_poly(th_);                                    \
      float kk_ = fmaf(gt_, ra[i2_][r_],                            \
                       fmaf(-itv[i2_][r_], hhc[i2_][r_], u[i2_][r_])); \
      float ks_ = ksum[i2_][r_] + kk_;                              \
      float hn_ = tanh_f(fmaf(ks_, 0.16666667f, hst[i2_][r_]));     \
      hst[i2_][r_] = hn_;                                           \
      hhc[i2_][r_] = hn_;                                           \
      hv_[r_] = (f16)hn_;                                           \
    }                                                               \
    *(f16x4*)((DST) + c * 136 + jb[i2_]) = hv_;                     \
  }

#define ZACC { ga[0] = ZERO4; ra[0] = ZERO4; ga[1] = ZERO4; ra[1] = ZERO4; }

__global__ __launch_bounds__(512, 2) void ltc_kernel(
    const float* __restrict__ seq, const float* __restrict__ ctx,
    const float* __restrict__ tau0p, const float* __restrict__ bg0p,
    const float* __restrict__ tau1p, const float* __restrict__ bg1p,
    const float* __restrict__ W1, const float* __restrict__ b1,
    const float* __restrict__ W2, const float* __restrict__ b2,
    const f16* __restrict__ W, float* __restrict__ out) {
  __shared__ __align__(16) char smem[SMEM_BYTES];
  f16* hq0 = (f16*)(smem + HQ0);
  f16* hq1 = (f16*)(smem + HQ1);
  f16* l0a = (f16*)(smem + L0A);
  f16* l0b = (f16*)(smem + L0B);
  f16* l1a = (f16*)(smem + L1A);
  f16* l1b = (f16*)(smem + L1B);
  f16* l1h = (f16*)(smem + L1H);
  f16* xt0 = (f16*)(smem + XT0);
  f16* xt1 = (f16*)(smem + XT1);

  const int tid = threadIdx.x;
  const int w8 = tid >> 6, lane = tid & 63;
  const int q = lane >> 4, c = lane & 15;
  const int wl = w8 & 3;
  const bool isL0 = (w8 < 4);
  const int bg = blockIdx.x;
  int jb[2];
  jb[0] = 32 * wl + 4 * q;
  jb[1] = jb[0] + 16;

  f16* bufA = isL0 ? l0a : l1a;
  f16* bufB = isL0 ? l0b : l1b;

  // ---- weight fragments -> VGPRs (held for whole kernel) ----
  f16x8 awg[2][4], awr[2][4], au[2][4], ag2[2][4];
  f16x8 bctx;
  if (isL0) {
#pragma unroll
    for (int i2 = 0; i2 < 2; ++i2) {
      int T = 2 * wl + i2;
#pragma unroll
      for (int kc = 0; kc < 4; ++kc) {
        awg[i2][kc] = *(const f16x8*)(W + OFF_A0 + (((T * 2 + 0) * 4 + kc) * 64 + lane) * 8);
        awr[i2][kc] = *(const f16x8*)(W + OFF_A0 + (((T * 2 + 1) * 4 + kc) * 64 + lane) * 8);
      }
#pragma unroll
      for (int kc = 0; kc < 3; ++kc) {
        au[i2][kc] = *(const f16x8*)(W + OFF_AX + (((T * 2 + 0) * 3 + kc) * 64 + lane) * 8);
        ag2[i2][kc] = *(const f16x8*)(W + OFF_AX + (((T * 2 + 1) * 3 + kc) * 64 + lane) * 8);
      }
      au[i2][3] = (f16x8)(f16)0.f;
      ag2[i2][3] = (f16x8)(f16)0.f;
    }
    const float* cp = ctx + (bg * 16 + c) * 32 + 8 * q;
#pragma unroll
    for (int j = 0; j < 8; ++j) bctx[j] = (f16)cp[j];
  } else {
#pragma unroll
    for (int i2 = 0; i2 < 2; ++i2) {
      int T = 2 * wl + i2;
#pragma unroll
      for (int kc = 0; kc < 4; ++kc) {
        awg[i2][kc] = *(const f16x8*)(W + OFF_A1 + (((T * 2 + 0) * 4 + kc) * 64 + lane) * 8);
        awr[i2][kc] = *(const f16x8*)(W + OFF_A1 + (((T * 2 + 1) * 4 + kc) * 64 + lane) * 8);
        au[i2][kc] = *(const f16x8*)(W + OFF_AIO + (((T * 2 + 0) * 4 + kc) * 64 + lane) * 8);
        ag2[i2][kc] = *(const f16x8*)(W + OFF_AIO + (((T * 2 + 1) * 4 + kc) * 64 + lane) * 8);
      }
    }
  }

  // per-lane params for the 8 owned rows
  const float* taup = isL0 ? tau0p : tau1p;
  const float* bgp = isL0 ? bg0p : bg1p;
  f32x4 itv[2], bgv[2];
#pragma unroll
  for (int i2 = 0; i2 < 2; ++i2)
#pragma unroll
    for (int r = 0; r < 4; ++r) {
      float t = taup[jb[i2] + r];
      itv[i2][r] = 1.f / (logf(1.f + __expf(t)) + 1.f);  // 1/(softplus+1)
      bgv[i2][r] = bgp[jb[i2] + r];
    }

  f32x4 hst[2], hhc[2], u[2], gx[2], ksum[2], ga[2], ra[2];
  f32x4 un[2], gxn[2];
  hst[0] = hst[1] = hhc[0] = hhc[1] = ZERO4;
  ksum[0] = ksum[1] = ZERO4;
  un[0] = un[1] = gxn[0] = gxn[1] = ZERO4;

  // zero initial-state buffers: hq1 (h0 at t=-1) and l1h (h1 at t=-1)
  for (int j = tid; j < 2176; j += 512) {
    hq1[j] = (f16)0.f;
    l1h[j] = (f16)0.f;
  }
  // pre-stage x(0) into xt0; issue load of x(1) into sq_nxt
  const int bs = tid >> 4, fp = tid & 15;
  const size_t seqrow = ((size_t)(bg * 16 + bs)) * NSTEP * 64 + 4 * fp;
  float4 sq_nxt = {0.f, 0.f, 0.f, 0.f};
  float4 sq_ld = sq_nxt;
  if (tid < 256) {
    float4 sv = *(const float4*)(seq + seqrow);
    *(f16x4*)(xt0 + bs * 72 + 4 * fp) =
        (f16x4){(f16)sv.x, (f16)sv.y, (f16)sv.z, (f16)sv.w};
    sq_nxt = *(const float4*)(seq + seqrow + 64);  // x(1)
  }
  __syncthreads();
  // u/gx for step 0 (pipeline warm-up)
  if (isL0) { XPROJ(xt0, u, gx); }

#pragma unroll 1
  for (int i = 0; i <= NSTEP; ++i) {
    const f16* hprev = ((i + 1) & 1) ? hq1 : hq0;  // h0(t-1) buffer
    f16* xw = ((i + 1) & 1) ? xt1 : xt0;           // buffer for x(i+1)

    // ===== slot A: L0 stage1 (+stage x(i+1), issue x(i+2)) | L1 io + stage1
    if (isL0) {
      if (i < NSTEP) {
        if (i + 2 < NSTEP)
          sq_ld = *(const float4*)(seq + seqrow + (size_t)(i + 2) * 64);
        ZACC;
        MM2(hprev);  // stage 1 on h0(t-1) -- the critical prefix
        if (i + 1 < NSTEP)
          *(f16x4*)(xw + bs * 72 + 4 * fp) =
              (f16x4){(f16)sq_nxt.x, (f16)sq_nxt.y, (f16)sq_nxt.z, (f16)sq_nxt.w};
        ksum[0] = ZERO4; ksum[1] = ZERO4;
        GATEALL(1.0f, 0.5f, bufA);
      }
    } else {
      if (i >= 1) {
        ZACC;
        MMIO(hprev, 4);  // u1 = Win1*h0_new, g1x = Wg1x*h0_new
#pragma unroll
        for (int i2 = 0; i2 < 2; ++i2) {
          u[i2] = ga[i2];
#pragma unroll
          for (int r = 0; r < 4; ++r) gx[i2][r] = ra[i2][r] + bgv[i2][r];
        }
        ZACC;
        MM2(l1h);  // stage 1 on h1(t-2)
        ksum[0] = ZERO4; ksum[1] = ZERO4;
        GATEALL(1.0f, 0.5f, bufA);
      }
    }
    BAR();

    // ===== slot B: stage 2 ; L0 also computes x-proj(i+1) off-path =====
    if (isL0) {
      if (i < NSTEP) {
        ZACC;
        MM2(bufA);
        GATEALL(2.0f, 0.5f, bufB);
        if (i + 1 < NSTEP) { XPROJ(xw, un, gxn); }
      }
    } else if (i >= 1) {
      ZACC;
      MM2(bufA);
      GATEALL(2.0f, 0.5f, bufB);
    }
    BAR();

    // ===== slot C: stage 3 =====
    if ((isL0 && i < NSTEP) || (!isL0 && i >= 1)) {
      ZACC;
      MM2(bufB);
      GATEALL(2.0f, 1.0f, bufA);
    }
    BAR();

    // ===== slot D: stage 4 -> h_new; L0 commits pipelined u/gx + seq reg =====
    if (isL0) {
      if (i < NSTEP) {
        ZACC;
        MM2(bufA);
        GATEFIN((i & 1) ? hq1 : hq0);
        if (i + 1 < NSTEP) {
          u[0] = un[0]; u[1] = un[1];
          gx[0] = gxn[0]; gx[1] = gxn[1];
          if (i + 2 < NSTEP) sq_nxt = sq_ld;
        }
      }
    } else if (i >= 1) {
      ZACC;
      MM2(bufA);
      GATEFIN(l1h);
    }
    BAR();
  }

  // ======================= classifier epilogue ===========================
  float* h1f = (float*)smem;  // [16][132] f32
  if (!isL0) {
#pragma unroll
    for (int i2 = 0; i2 < 2; ++i2)
      *(f32x4*)(h1f + c * 132 + jb[i2]) = hst[i2];
  }
  __syncthreads();
  float* z1 = (float*)(smem + 16 * 132 * 4);  // [16][64] f32
  {
    int b = tid >> 5, o = tid & 31;
#pragma unroll
    for (int hlf = 0; hlf < 2; ++hlf) {
      int oo = o + 32 * hlf;
      const float* wr = W1 + oo * 128;
      const float* hr = h1f + b * 132;
      float s = 0.f;
#pragma unroll
      for (int j = 0; j < 128; j += 4) {
        f32x4 wv = *(const f32x4*)(wr + j);
        f32x4 hv = *(const f32x4*)(hr + j);
        s += wv[0] * hv[0] + wv[1] * hv[1] + wv[2] * hv[2] + wv[3] * hv[3];
      }
      s += b1[oo];
      z1[b * 64 + oo] = fmaxf(s, 0.f);
    }
  }
  __syncthreads();
  if (tid < 16) {
    float s = b2[0];
#pragma unroll
    for (int o = 0; o < 64; ++o) s += z1[tid * 64 + o] * W2[o];
    out[bg * 16 + tid] = rcp_f(1.f + __expf(-s));
  }
}

extern "C" void kernel_launch(void* const* d_in, const int* in_sizes, int n_in,
                              void* d_out, int out_size, void* d_ws, size_t ws_size,
                              hipStream_t stream) {
  (void)in_sizes; (void)n_in; (void)out_size; (void)ws_size;
  const float* seq = (const float*)d_in[0];
  const float* ctx = (const float*)d_in[1];
  const float* tau0 = (const float*)d_in[2];
  const float* Win0 = (const float*)d_in[3];
  const float* Wrec0 = (const float*)d_in[4];
  const float* Wg0 = (const float*)d_in[5];
  const float* bg0 = (const float*)d_in[6];
  const float* tau1 = (const float*)d_in[7];
  const float* Win1 = (const float*)d_in[8];
  const float* Wrec1 = (const float*)d_in[9];
  const float* Wg1 = (const float*)d_in[10];
  const float* bg1 = (const float*)d_in[11];
  const float* W1 = (const float*)d_in[12];
  const float* b1 = (const float*)d_in[13];
  const float* W2 = (const float*)d_in[14];
  const float* b2 = (const float*)d_in[15];
  f16* W = (f16*)d_ws;  // 245760 B of packed fragments

  prep_kernel<<<480, 256, 0, stream>>>(Win0, Wrec0, Wg0, Win1, Wrec1, Wg1, W);
  ltc_kernel<<<32, 512, 0, stream>>>(seq, ctx, tau0, bg0, tau1, bg1, W1, b1, W2,
                                     b2, W, (float*)d_out);
}

// Round 3
// 1921.998 us; speedup vs baseline: 1.0218x; 1.0022x over previous
//
#include <hip/hip_runtime.h>

// LTC RNN (LiquidNeuralNetwork): B=512, S=512, H=128, 2 layers, RK4.
// Round 5 = round 4 resubmitted (round-4 bench died on container acquire, no
// kernel evidence). Change vs round 3: __launch_bounds__(512,2) -> (512,1).
// The (512,2) bound capped VGPR_Count at 128 while the live set is ~128 regs
// of weight frags + ~110 VGPRs of state, leaving ~0 temporaries: the compiler
// serialized B-frag loads (4x ds_read round-trips/slot) and the 8 gate-element
// chains (~800 cy serial). Grid is 32 blocks on 256 CUs (1 block/CU), so
// min-waves=2 buys nothing: with (512,1) each wave may use up to 512 unified
// regs and the 8-wave workgroup (2 waves/SIMD) always fits (2x512 <= 2048).
// (Round 3 kept: lgkm-only barriers, x-proj pipelined into slot B.)

typedef _Float16 f16;
typedef _Float16 f16x4 __attribute__((ext_vector_type(4)));
typedef _Float16 f16x8 __attribute__((ext_vector_type(8)));
typedef float f32x4 __attribute__((ext_vector_type(4)));

#define NSTEP 512
#define OFF_A0 0
#define OFF_A1 32768
#define OFF_AIO 65536
#define OFF_AX 98304
#define W_TOTAL 122880

// LDS byte offsets. hh buffers: [16 cols][136 f16] = 4352 B each.
#define HQ0 0
#define HQ1 4352
#define L0A 8704
#define L0B 13056
#define L1A 17408
#define L1B 21760
#define L1H 26112
#define XT0 30464
#define XT1 32768
#define SMEM_BYTES 35072

__device__ __forceinline__ float rcp_f(float x) { return __builtin_amdgcn_rcpf(x); }
__device__ __forceinline__ float tanh_f(float x) {
  float e = __expf(2.f * x);
  return 1.f - 2.f * rcp_f(e + 1.f);
}
// sigmoid(t) for t in [-1,1] (t = tanh(...)): odd Taylor of 0.5+0.5*tanh(t/2), |err|<3e-6
__device__ __forceinline__ float sig_poly(float t) {
  float s = t * t;
  float p = fmaf(s, 2.1356861e-5f, -2.1081349e-4f);
  p = fmaf(s, p, 2.0833333e-3f);
  p = fmaf(s, p, -2.0833333e-2f);
  p = fmaf(s, p, 0.25f);
  return fmaf(t, p, 0.5f);
}

// lgkm-only barrier: LDS produce->consume needs lgkmcnt(0)+s_barrier only.
// Crucially does NOT drain vmcnt, so seq prefetch loads stay in flight.
#define BAR()                                            \
  do {                                                   \
    asm volatile("s_waitcnt lgkmcnt(0)" ::: "memory");   \
    __builtin_amdgcn_s_barrier();                        \
  } while (0)

// Pack all recurrent-loop weights into f16 MFMA A-fragments.
// A-frag (16x16x32): A[m=lane&15][k=(lane>>4)*8+j], row-tile T = rows 16T..16T+15.
// A0 @0      [T8][sel2][kc4][lane64][j8]  sel0=Wg0 h-part, sel1=Wrec0
// A1 @32768  same                          sel0=Wg1 h-part, sel1=Wrec1
// AIO@65536  same                          sel0=Win1,       sel1=Wg1 x-part
// AX @98304  [T8][sel2][kc3][lane64][j8]  sel0=Win0,       sel1=Wg0 x-part (K=96)
__global__ __launch_bounds__(256) void prep_kernel(
    const float* __restrict__ Win0, const float* __restrict__ Wrec0,
    const float* __restrict__ Wg0, const float* __restrict__ Win1,
    const float* __restrict__ Wrec1, const float* __restrict__ Wg1,
    f16* __restrict__ W) {
  int i = blockIdx.x * 256 + threadIdx.x;
  if (i >= W_TOTAL) return;
  if (i < OFF_AX) {
    int sec = i >> 15;
    int r = i & 32767;
    int j = r & 7, lane = (r >> 3) & 63, kc = (r >> 9) & 3, sel = (r >> 11) & 1,
        w = (r >> 12) & 7;
    int row = w * 16 + (lane & 15);
    int k = kc * 32 + ((lane >> 4) << 3) + j;
    float v;
    if (sec == 0)
      v = sel ? Wrec0[row * 128 + k] : Wg0[row * 224 + 96 + k];
    else if (sec == 1)
      v = sel ? Wrec1[row * 128 + k] : Wg1[row * 256 + 128 + k];
    else
      v = sel ? Wg1[row * 256 + k] : Win1[row * 128 + k];
    W[i] = (f16)v;
  } else {
    int r = i - OFF_AX;
    int j = r & 7, lane = (r >> 3) & 63, g = r >> 9;
    int kc = g % 3, sg = g / 3;
    int sel = sg & 1, w = sg >> 1;
    int row = w * 16 + (lane & 15);
    int k = kc * 32 + ((lane >> 4) << 3) + j;
    W[i] = (f16)(sel ? Wg0[row * 224 + k] : Win0[row * 96 + k]);
  }
}

#define MFMA16(A, B, C) __builtin_amdgcn_mfma_f32_16x16x32_f16((A), (B), (C), 0, 0, 0)
#define ZERO4 ((f32x4){0.f, 0.f, 0.f, 0.f})

// 2-tile matvec accumulate: ga/ra[i2] += {awg,awr}[i2] * B-frag(SRC). One B-frag
// read feeds 4 MFMAs (the round-2 LDS amortization).
#define MM2(SRC)                                                    \
  {                                                                 \
    const f16* bp_ = (SRC) + c * 136 + 8 * q;                       \
    _Pragma("unroll") for (int kc_ = 0; kc_ < 4; ++kc_) {           \
      f16x8 bf_ = *(const f16x8*)(bp_ + kc_ * 32);                  \
      ga[0] = MFMA16(awg[0][kc_], bf_, ga[0]);                      \
      ra[0] = MFMA16(awr[0][kc_], bf_, ra[0]);                      \
      ga[1] = MFMA16(awg[1][kc_], bf_, ga[1]);                      \
      ra[1] = MFMA16(awr[1][kc_], bf_, ra[1]);                      \
    }                                                               \
  }

// io / input projection with the au/ag2 fragment set (KCN k-chunks) into ga/ra.
#define MMIO(SRC, KCN)                                              \
  {                                                                 \
    const f16* bp_ = (SRC) + c * 136 + 8 * q;                       \
    _Pragma("unroll") for (int kc_ = 0; kc_ < (KCN); ++kc_) {       \
      f16x8 bf_ = *(const f16x8*)(bp_ + kc_ * 32);                  \
      ga[0] = MFMA16(au[0][kc_], bf_, ga[0]);                       \
      ra[0] = MFMA16(ag2[0][kc_], bf_, ra[0]);                      \
      ga[1] = MFMA16(au[1][kc_], bf_, ga[1]);                       \
      ra[1] = MFMA16(ag2[1][kc_], bf_, ra[1]);                      \
    }                                                               \
  }

// L0 x-projection (K=96: 2 chunks from x-tile + ctx) -> UD (=Win0*x),
// GD (=Wg0x*x + bg). Uses ga/ra as temporaries; off the recurrent path.
#define XPROJ(XSRC, UD, GD)                                         \
  {                                                                 \
    ZACC;                                                           \
    f16x8 bx0_ = *(const f16x8*)((XSRC) + c * 72 + 8 * q);          \
    f16x8 bx1_ = *(const f16x8*)((XSRC) + c * 72 + 32 + 8 * q);     \
    _Pragma("unroll") for (int i2_ = 0; i2_ < 2; ++i2_) {           \
      ga[i2_] = MFMA16(au[i2_][0], bx0_, ga[i2_]);                  \
      ra[i2_] = MFMA16(ag2[i2_][0], bx0_, ra[i2_]);                 \
      ga[i2_] = MFMA16(au[i2_][1], bx1_, ga[i2_]);                  \
      ra[i2_] = MFMA16(ag2[i2_][1], bx1_, ra[i2_]);                 \
      ga[i2_] = MFMA16(au[i2_][2], bctx, ga[i2_]);                  \
      ra[i2_] = MFMA16(ag2[i2_][2], bctx, ra[i2_]);                 \
      (UD)[i2_] = ga[i2_];                                          \
      _Pragma("unroll") for (int r_ = 0; r_ < 4; ++r_)              \
        (GD)[i2_][r_] = ra[i2_][r_] + bgv[i2_][r_];                 \
    }                                                               \
  }

// RK stage body: gate math on 8 (gate,rec) pairs, ksum += WC*k, eval point
// hhc = h + HC*k, write f16 eval point to DST.
#define GATEALL(WC, HC, DST)                                        \
  _Pragma("unroll") for (int i2_ = 0; i2_ < 2; ++i2_) {             \
    f16x4 hv_;                                                      \
    _Pragma("unroll") for (int r_ = 0; r_ < 4; ++r_) {              \
      float th_ = tanh_f(ga[i2_][r_] + gx[i2_][r_]);                \
      float gt_ = sig_poly(th_);                                    \
      float kk_ = fmaf(gt_, ra[i2_][r_],                            \
                       fmaf(-itv[i2_][r_], hhc[i2_][r_], u[i2_][r_])); \
      ksum[i2_][r_] = fmaf((WC), kk_, ksum[i2_][r_]);               \
      float hn_ = fmaf((HC), kk_, hst[i2_][r_]);                    \
      hhc[i2_][r_] = hn_;                                           \
      hv_[r_] = (f16)hn_;                                           \
    }                                                               \
    *(f16x4*)((DST) + c * 136 + jb[i2_]) = hv_;                     \
  }

// RK stage 4: h_new = tanh(h + ksum/6), becomes both state and next stage-1 eval.
#define GATEFIN(DST)                                                \
  _Pragma("unroll") for (int i2_ = 0; i2_ < 2; ++i2_) {             \
    f16x4 hv_;                                                      \
    _Pragma("unroll") for (int r_ = 0; r_ < 4; ++r_) {              \
      float th_ = tanh_f(ga[i2_][r_] + gx[i2_][r_]);                \
      float gt_ = sig_poly(th_);                                    \
      float kk_ = fmaf(gt_, ra[i2_][r_],                            \
                       fmaf(-itv[i2_][r_], hhc[i2_][r_], u[i2_][r_])); \
      float ks_ = ksum[i2_][r_] + kk_;                              \
      float hn_ = tanh_f(fmaf(ks_, 0.16666667f, hst[i2_][r_]));     \
      hst[i2_][r_] = hn_;                                           \
      hhc[i2_][r_] = hn_;                                           \
      hv_[r_] = (f16)hn_;                                           \
    }                                                               \
    *(f16x4*)((DST) + c * 136 + jb[i2_]) = hv_;                     \
  }

#define ZACC { ga[0] = ZERO4; ra[0] = ZERO4; ga[1] = ZERO4; ra[1] = ZERO4; }

__global__ __launch_bounds__(512, 1) void ltc_kernel(
    const float* __restrict__ seq, const float* __restrict__ ctx,
    const float* __restrict__ tau0p, const float* __restrict__ bg0p,
    const float* __restrict__ tau1p, const float* __restrict__ bg1p,
    const float* __restrict__ W1, const float* __restrict__ b1,
    const float* __restrict__ W2, const float* __restrict__ b2,
    const f16* __restrict__ W, float* __restrict__ out) {
  __shared__ __align__(16) char smem[SMEM_BYTES];
  f16* hq0 = (f16*)(smem + HQ0);
  f16* hq1 = (f16*)(smem + HQ1);
  f16* l0a = (f16*)(smem + L0A);
  f16* l0b = (f16*)(smem + L0B);
  f16* l1a = (f16*)(smem + L1A);
  f16* l1b = (f16*)(smem + L1B);
  f16* l1h = (f16*)(smem + L1H);
  f16* xt0 = (f16*)(smem + XT0);
  f16* xt1 = (f16*)(smem + XT1);

  const int tid = threadIdx.x;
  const int w8 = tid >> 6, lane = tid & 63;
  const int q = lane >> 4, c = lane & 15;
  const int wl = w8 & 3;
  const bool isL0 = (w8 < 4);
  const int bg = blockIdx.x;
  int jb[2];
  jb[0] = 32 * wl + 4 * q;
  jb[1] = jb[0] + 16;

  f16* bufA = isL0 ? l0a : l1a;
  f16* bufB = isL0 ? l0b : l1b;

  // ---- weight fragments -> VGPRs (held for whole kernel) ----
  f16x8 awg[2][4], awr[2][4], au[2][4], ag2[2][4];
  f16x8 bctx;
  if (isL0) {
#pragma unroll
    for (int i2 = 0; i2 < 2; ++i2) {
      int T = 2 * wl + i2;
#pragma unroll
      for (int kc = 0; kc < 4; ++kc) {
        awg[i2][kc] = *(const f16x8*)(W + OFF_A0 + (((T * 2 + 0) * 4 + kc) * 64 + lane) * 8);
        awr[i2][kc] = *(const f16x8*)(W + OFF_A0 + (((T * 2 + 1) * 4 + kc) * 64 + lane) * 8);
      }
#pragma unroll
      for (int kc = 0; kc < 3; ++kc) {
        au[i2][kc] = *(const f16x8*)(W + OFF_AX + (((T * 2 + 0) * 3 + kc) * 64 + lane) * 8);
        ag2[i2][kc] = *(const f16x8*)(W + OFF_AX + (((T * 2 + 1) * 3 + kc) * 64 + lane) * 8);
      }
      au[i2][3] = (f16x8)(f16)0.f;
      ag2[i2][3] = (f16x8)(f16)0.f;
    }
    const float* cp = ctx + (bg * 16 + c) * 32 + 8 * q;
#pragma unroll
    for (int j = 0; j < 8; ++j) bctx[j] = (f16)cp[j];
  } else {
#pragma unroll
    for (int i2 = 0; i2 < 2; ++i2) {
      int T = 2 * wl + i2;
#pragma unroll
      for (int kc = 0; kc < 4; ++kc) {
        awg[i2][kc] = *(const f16x8*)(W + OFF_A1 + (((T * 2 + 0) * 4 + kc) * 64 + lane) * 8);
        awr[i2][kc] = *(const f16x8*)(W + OFF_A1 + (((T * 2 + 1) * 4 + kc) * 64 + lane) * 8);
        au[i2][kc] = *(const f16x8*)(W + OFF_AIO + (((T * 2 + 0) * 4 + kc) * 64 + lane) * 8);
        ag2[i2][kc] = *(const f16x8*)(W + OFF_AIO + (((T * 2 + 1) * 4 + kc) * 64 + lane) * 8);
      }
    }
  }

  // per-lane params for the 8 owned rows
  const float* taup = isL0 ? tau0p : tau1p;
  const float* bgp = isL0 ? bg0p : bg1p;
  f32x4 itv[2], bgv[2];
#pragma unroll
  for (int i2 = 0; i2 < 2; ++i2)
#pragma unroll
    for (int r = 0; r < 4; ++r) {
      float t = taup[jb[i2] + r];
      itv[i2][r] = 1.f / (logf(1.f + __expf(t)) + 1.f);  // 1/(softplus+1)
      bgv[i2][r] = bgp[jb[i2] + r];
    }

  f32x4 hst[2], hhc[2], u[2], gx[2], ksum[2], ga[2], ra[2];
  f32x4 un[2], gxn[2];
  hst[0] = hst[1] = hhc[0] = hhc[1] = ZERO4;
  ksum[0] = ksum[1] = ZERO4;
  un[0] = un[1] = gxn[0] = gxn[1] = ZERO4;

  // zero initial-state buffers: hq1 (h0 at t=-1) and l1h (h1 at t=-1)
  for (int j = tid; j < 2176; j += 512) {
    hq1[j] = (f16)0.f;
    l1h[j] = (f16)0.f;
  }
  // pre-stage x(0) into xt0; issue load of x(1) into sq_nxt
  const int bs = tid >> 4, fp = tid & 15;
  const size_t seqrow = ((size_t)(bg * 16 + bs)) * NSTEP * 64 + 4 * fp;
  float4 sq_nxt = {0.f, 0.f, 0.f, 0.f};
  float4 sq_ld = sq_nxt;
  if (tid < 256) {
    float4 sv = *(const float4*)(seq + seqrow);
    *(f16x4*)(xt0 + bs * 72 + 4 * fp) =
        (f16x4){(f16)sv.x, (f16)sv.y, (f16)sv.z, (f16)sv.w};
    sq_nxt = *(const float4*)(seq + seqrow + 64);  // x(1)
  }
  __syncthreads();
  // u/gx for step 0 (pipeline warm-up)
  if (isL0) { XPROJ(xt0, u, gx); }

#pragma unroll 1
  for (int i = 0; i <= NSTEP; ++i) {
    const f16* hprev = ((i + 1) & 1) ? hq1 : hq0;  // h0(t-1) buffer
    f16* xw = ((i + 1) & 1) ? xt1 : xt0;           // buffer for x(i+1)

    // ===== slot A: L0 stage1 (+stage x(i+1), issue x(i+2)) | L1 io + stage1
    if (isL0) {
      if (i < NSTEP) {
        if (i + 2 < NSTEP)
          sq_ld = *(const float4*)(seq + seqrow + (size_t)(i + 2) * 64);
        ZACC;
        MM2(hprev);  // stage 1 on h0(t-1) -- the critical prefix
        if (i + 1 < NSTEP)
          *(f16x4*)(xw + bs * 72 + 4 * fp) =
              (f16x4){(f16)sq_nxt.x, (f16)sq_nxt.y, (f16)sq_nxt.z, (f16)sq_nxt.w};
        ksum[0] = ZERO4; ksum[1] = ZERO4;
        GATEALL(1.0f, 0.5f, bufA);
      }
    } else {
      if (i >= 1) {
        ZACC;
        MMIO(hprev, 4);  // u1 = Win1*h0_new, g1x = Wg1x*h0_new
#pragma unroll
        for (int i2 = 0; i2 < 2; ++i2) {
          u[i2] = ga[i2];
#pragma unroll
          for (int r = 0; r < 4; ++r) gx[i2][r] = ra[i2][r] + bgv[i2][r];
        }
        ZACC;
        MM2(l1h);  // stage 1 on h1(t-2)
        ksum[0] = ZERO4; ksum[1] = ZERO4;
        GATEALL(1.0f, 0.5f, bufA);
      }
    }
    BAR();

    // ===== slot B: stage 2 ; L0 also computes x-proj(i+1) off-path =====
    if (isL0) {
      if (i < NSTEP) {
        ZACC;
        MM2(bufA);
        GATEALL(2.0f, 0.5f, bufB);
        if (i + 1 < NSTEP) { XPROJ(xw, un, gxn); }
      }
    } else if (i >= 1) {
      ZACC;
      MM2(bufA);
      GATEALL(2.0f, 0.5f, bufB);
    }
    BAR();

    // ===== slot C: stage 3 =====
    if ((isL0 && i < NSTEP) || (!isL0 && i >= 1)) {
      ZACC;
      MM2(bufB);
      GATEALL(2.0f, 1.0f, bufA);
    }
    BAR();

    // ===== slot D: stage 4 -> h_new; L0 commits pipelined u/gx + seq reg =====
    if (isL0) {
      if (i < NSTEP) {
        ZACC;
        MM2(bufA);
        GATEFIN((i & 1) ? hq1 : hq0);
        if (i + 1 < NSTEP) {
          u[0] = un[0]; u[1] = un[1];
          gx[0] = gxn[0]; gx[1] = gxn[1];
          if (i + 2 < NSTEP) sq_nxt = sq_ld;
        }
      }
    } else if (i >= 1) {
      ZACC;
      MM2(bufA);
      GATEFIN(l1h);
    }
    BAR();
  }

  // ======================= classifier epilogue ===========================
  float* h1f = (float*)smem;  // [16][132] f32
  if (!isL0) {
#pragma unroll
    for (int i2 = 0; i2 < 2; ++i2)
      *(f32x4*)(h1f + c * 132 + jb[i2]) = hst[i2];
  }
  __syncthreads();
  float* z1 = (float*)(smem + 16 * 132 * 4);  // [16][64] f32
  {
    int b = tid >> 5, o = tid & 31;
#pragma unroll
    for (int hlf = 0; hlf < 2; ++hlf) {
      int oo = o + 32 * hlf;
      const float* wr = W1 + oo * 128;
      const float* hr = h1f + b * 132;
      float s = 0.f;
#pragma unroll
      for (int j = 0; j < 128; j += 4) {
        f32x4 wv = *(const f32x4*)(wr + j);
        f32x4 hv = *(const f32x4*)(hr + j);
        s += wv[0] * hv[0] + wv[1] * hv[1] + wv[2] * hv[2] + wv[3] * hv[3];
      }
      s += b1[oo];
      z1[b * 64 + oo] = fmaxf(s, 0.f);
    }
  }
  __syncthreads();
  if (tid < 16) {
    float s = b2[0];
#pragma unroll
    for (int o = 0; o < 64; ++o) s += z1[tid * 64 + o] * W2[o];
    out[bg * 16 + tid] = rcp_f(1.f + __expf(-s));
  }
}

extern "C" void kernel_launch(void* const* d_in, const int* in_sizes, int n_in,
                              void* d_out, int out_size, void* d_ws, size_t ws_size,
                              hipStream_t stream) {
  (void)in_sizes; (void)n_in; (void)out_size; (void)ws_size;
  const float* seq = (const float*)d_in[0];
  const float* ctx = (const float*)d_in[1];
  const float* tau0 = (const float*)d_in[2];
  const float* Win0 = (const float*)d_in[3];
  const float* Wrec0 = (const float*)d_in[4];
  const float* Wg0 = (const float*)d_in[5];
  const float* bg0 = (const float*)d_in[6];
  const float* tau1 = (const float*)d_in[7];
  const float* Win1 = (const float*)d_in[8];
  const float* Wrec1 = (const float*)d_in[9];
  const float* Wg1 = (const float*)d_in[10];
  const float* bg1 = (const float*)d_in[11];
  const float* W1 = (const float*)d_in[12];
  const float* b1 = (const float*)d_in[13];
  const float* W2 = (const float*)d_in[14];
  const float* b2 = (const float*)d_in[15];
  f16* W = (f16*)d_ws;  // 245760 B of packed fragments

  prep_kernel<<<480, 256, 0, stream>>>(Win0, Wrec0, Wg0, Win1, Wrec1, Wg1, W);
  ltc_kernel<<<32, 512, 0, stream>>>(seq, ctx, tau0, bg0, tau1, bg1, W1, b1, W2,
                                     b2, W, (float*)d_out);
}